// Round 1
// baseline (367.633 us; speedup 1.0000x reference)
//
#include <hip/hip_runtime.h>
#include <math.h>

typedef __bf16 bf16x8 __attribute__((ext_vector_type(8)));
typedef float  f32x4  __attribute__((ext_vector_type(4)));

constexpr int B_ = 2, S_ = 512, D_ = 512, H_ = 8, HD_ = 64, FFN_ = 2048;
constexpr int NC_ = S_ / 64;          // 8 chunks of 64
constexpr float EPS_ = 1e-6f;

__device__ __forceinline__ __bf16 f2bf(float f) {
    union { float f; unsigned u; } x; x.f = f;
    unsigned r = (x.u + 0x7fffu + ((x.u >> 16) & 1u)) >> 16;
    union { unsigned short s; __bf16 b; } y; y.s = (unsigned short)r;
    return y.b;
}

// ---------------- RMSNorm: one block per row, D=512, 128 thr * float4 -------
__global__ __launch_bounds__(128) void rmsnorm_k(const float* __restrict__ X,
                                                 const float* __restrict__ g,
                                                 float* __restrict__ O) {
    int row = blockIdx.x, tid = threadIdx.x;
    float4 v = ((const float4*)(X + (size_t)row * D_))[tid];
    float ss = v.x*v.x + v.y*v.y + v.z*v.z + v.w*v.w;
    for (int off = 32; off > 0; off >>= 1) ss += __shfl_down(ss, off, 64);
    __shared__ float sred[2];
    if ((tid & 63) == 0) sred[tid >> 6] = ss;
    __syncthreads();
    float r = rsqrtf((sred[0] + sred[1]) / (float)D_ + EPS_);
    float4 gg = ((const float4*)g)[tid];
    float4 o; o.x = v.x*r*gg.x; o.y = v.y*r*gg.y; o.z = v.z*r*gg.z; o.w = v.w*r*gg.w;
    ((float4*)(O + (size_t)row * D_))[tid] = o;
}

// ---------------- bf16 MFMA GEMM: C[M,N] = act(A@B + bias + res) ------------
// 64x64 tile / block, 4 waves, each wave 16 rows x 64 cols. K step 32.
constexpr int LDT = 40;   // padded LDS k-stride (bf16 elems): 80B rows, 16B-aligned

__global__ __launch_bounds__(256) void gemm_k(const float* __restrict__ A,
                                              const float* __restrict__ Bm,
                                              float* __restrict__ C,
                                              int M, int N, int K,
                                              const float* __restrict__ bias,
                                              const float* __restrict__ res,
                                              int act) {
    __shared__ __bf16 sA[64][LDT];
    __shared__ __bf16 sB[64][LDT];   // transposed: [n][k]
    const int tid = threadIdx.x;
    const int wave = tid >> 6, lane = tid & 63;
    const int m0 = blockIdx.y * 64, n0 = blockIdx.x * 64;
    f32x4 acc[4] = {};

    const int arow = tid >> 2, acol = (tid & 3) * 8;   // A: 64 rows x 32 k
    const int bk = tid >> 3, bn = (tid & 7) * 8;       // B: 32 k x 64 n

    for (int kk = 0; kk < K; kk += 32) {
        {
            const float* p = A + (size_t)(m0 + arow) * K + kk + acol;
            float4 a0 = *(const float4*)p, a1 = *(const float4*)(p + 4);
            bf16x8 w;
            w[0]=f2bf(a0.x); w[1]=f2bf(a0.y); w[2]=f2bf(a0.z); w[3]=f2bf(a0.w);
            w[4]=f2bf(a1.x); w[5]=f2bf(a1.y); w[6]=f2bf(a1.z); w[7]=f2bf(a1.w);
            *(bf16x8*)&sA[arow][acol] = w;
        }
        {
            const float* p = Bm + (size_t)(kk + bk) * N + n0 + bn;
            float4 b0 = *(const float4*)p, b1 = *(const float4*)(p + 4);
            sB[bn+0][bk] = f2bf(b0.x); sB[bn+1][bk] = f2bf(b0.y);
            sB[bn+2][bk] = f2bf(b0.z); sB[bn+3][bk] = f2bf(b0.w);
            sB[bn+4][bk] = f2bf(b1.x); sB[bn+5][bk] = f2bf(b1.y);
            sB[bn+6][bk] = f2bf(b1.z); sB[bn+7][bk] = f2bf(b1.w);
        }
        __syncthreads();
        const int qk = (lane >> 4) * 8;
        bf16x8 af = *(const bf16x8*)&sA[wave * 16 + (lane & 15)][qk];
#pragma unroll
        for (int nt = 0; nt < 4; ++nt) {
            bf16x8 bf = *(const bf16x8*)&sB[nt * 16 + (lane & 15)][qk];
            acc[nt] = __builtin_amdgcn_mfma_f32_16x16x32_bf16(af, bf, acc[nt], 0, 0, 0);
        }
        __syncthreads();
    }
    const int r0 = wave * 16 + ((lane >> 4) << 2);
#pragma unroll
    for (int nt = 0; nt < 4; ++nt) {
        int col = n0 + nt * 16 + (lane & 15);
#pragma unroll
        for (int r = 0; r < 4; ++r) {
            int row = m0 + r0 + r;
            float v = acc[nt][r];
            if (bias) v += bias[col];
            if (res)  v += res[(size_t)row * N + col];
            if (act == 1) v = fmaxf(v, 0.f);
            C[(size_t)row * N + col] = v;
        }
    }
}

// ---------------- dual GEMM + silu(g)*u epilogue (FFN gate/up) --------------
__global__ __launch_bounds__(256) void gemm_dual_silu_k(const float* __restrict__ A,
                                                        const float* __restrict__ Bg,
                                                        const float* __restrict__ Bu,
                                                        float* __restrict__ Hout,
                                                        int M, int N, int K) {
    __shared__ __bf16 sA[64][LDT];
    __shared__ __bf16 sG[64][LDT];
    __shared__ __bf16 sU[64][LDT];
    const int tid = threadIdx.x;
    const int wave = tid >> 6, lane = tid & 63;
    const int m0 = blockIdx.y * 64, n0 = blockIdx.x * 64;
    f32x4 accg[4] = {}, accu[4] = {};
    const int arow = tid >> 2, acol = (tid & 3) * 8;
    const int bk = tid >> 3, bn = (tid & 7) * 8;

    for (int kk = 0; kk < K; kk += 32) {
        {
            const float* p = A + (size_t)(m0 + arow) * K + kk + acol;
            float4 a0 = *(const float4*)p, a1 = *(const float4*)(p + 4);
            bf16x8 w;
            w[0]=f2bf(a0.x); w[1]=f2bf(a0.y); w[2]=f2bf(a0.z); w[3]=f2bf(a0.w);
            w[4]=f2bf(a1.x); w[5]=f2bf(a1.y); w[6]=f2bf(a1.z); w[7]=f2bf(a1.w);
            *(bf16x8*)&sA[arow][acol] = w;
        }
        {
            const float* p = Bg + (size_t)(kk + bk) * N + n0 + bn;
            float4 b0 = *(const float4*)p, b1 = *(const float4*)(p + 4);
            sG[bn+0][bk] = f2bf(b0.x); sG[bn+1][bk] = f2bf(b0.y);
            sG[bn+2][bk] = f2bf(b0.z); sG[bn+3][bk] = f2bf(b0.w);
            sG[bn+4][bk] = f2bf(b1.x); sG[bn+5][bk] = f2bf(b1.y);
            sG[bn+6][bk] = f2bf(b1.z); sG[bn+7][bk] = f2bf(b1.w);
            p = Bu + (size_t)(kk + bk) * N + n0 + bn;
            b0 = *(const float4*)p; b1 = *(const float4*)(p + 4);
            sU[bn+0][bk] = f2bf(b0.x); sU[bn+1][bk] = f2bf(b0.y);
            sU[bn+2][bk] = f2bf(b0.z); sU[bn+3][bk] = f2bf(b0.w);
            sU[bn+4][bk] = f2bf(b1.x); sU[bn+5][bk] = f2bf(b1.y);
            sU[bn+6][bk] = f2bf(b1.z); sU[bn+7][bk] = f2bf(b1.w);
        }
        __syncthreads();
        const int qk = (lane >> 4) * 8;
        bf16x8 af = *(const bf16x8*)&sA[wave * 16 + (lane & 15)][qk];
#pragma unroll
        for (int nt = 0; nt < 4; ++nt) {
            bf16x8 bg = *(const bf16x8*)&sG[nt * 16 + (lane & 15)][qk];
            bf16x8 bu = *(const bf16x8*)&sU[nt * 16 + (lane & 15)][qk];
            accg[nt] = __builtin_amdgcn_mfma_f32_16x16x32_bf16(af, bg, accg[nt], 0, 0, 0);
            accu[nt] = __builtin_amdgcn_mfma_f32_16x16x32_bf16(af, bu, accu[nt], 0, 0, 0);
        }
        __syncthreads();
    }
    const int r0 = wave * 16 + ((lane >> 4) << 2);
#pragma unroll
    for (int nt = 0; nt < 4; ++nt) {
        int col = n0 + nt * 16 + (lane & 15);
#pragma unroll
        for (int r = 0; r < 4; ++r) {
            int row = m0 + r0 + r;
            float gv = accg[nt][r], uv = accu[nt][r];
            float hv = (gv / (1.f + expf(-gv))) * uv;
            Hout[(size_t)row * N + col] = hv;
        }
    }
}

// ---------------- scan phase A: per-chunk decayed outer-product sum ---------
// M_c = sum_t sp_t * v_t k_t^T ; sp_t = prod_{w=t+1..63} c_w ; P_c = prod c
__global__ __launch_bounds__(256) void scan_chunk_outer_k(const float* __restrict__ Kq,
                                                          const float* __restrict__ V,
                                                          const float* __restrict__ mask,
                                                          float* __restrict__ Mws,
                                                          float* __restrict__ Pws) {
    int bid = blockIdx.x;
    int c = bid & (NC_ - 1), h = (bid >> 3) & (H_ - 1), b = bid >> 6;
    __shared__ float sk[64][64], sv[64][64];
    __shared__ float scv[64], ssp[64];
    int tid = threadIdx.x;
    for (int it = 0; it < 4; ++it) {
        int idx = tid + it * 256;          // float4 index
        int t = idx >> 4, d4 = idx & 15;
        size_t base = ((size_t)(b * S_ + c * 64 + t) * (H_ * HD_)) + h * 64 + d4 * 4;
        *(float4*)&sk[t][d4 * 4] = *(const float4*)&Kq[base];
        *(float4*)&sv[t][d4 * 4] = *(const float4*)&V[base];
    }
    if (tid < 64) scv[tid] = 1.0f - mask[b * S_ + c * 64 + tid];
    __syncthreads();
    if (tid == 0) {
        float sp = 1.f;
        for (int t = 63; t >= 0; --t) { ssp[t] = sp; sp *= scv[t]; }
        Pws[bid] = sp;
    }
    __syncthreads();
    int i = tid >> 2, j0 = (tid & 3) * 16;
    float m[16];
#pragma unroll
    for (int jj = 0; jj < 16; ++jj) m[jj] = 0.f;
    for (int t = 0; t < 64; ++t) {
        float vv = sv[t][i] * ssp[t];
#pragma unroll
        for (int jj = 0; jj < 16; ++jj) m[jj] += vv * sk[t][j0 + jj];
    }
    float* mout = Mws + (size_t)bid * 4096 + i * 64 + j0;
    for (int jj = 0; jj < 16; ++jj) mout[jj] = m[jj];
}

// ---------------- scan phase B: inter-chunk prefix + final carry ------------
__global__ __launch_bounds__(256) void scan_prefix_k(const float* __restrict__ carry,
                                                     const float* __restrict__ Mws,
                                                     const float* __restrict__ Pws,
                                                     float* __restrict__ Sin,
                                                     float* __restrict__ carry_out) {
    int bh = blockIdx.x, tid = threadIdx.x;
    int i = tid >> 2, j0 = (tid & 3) * 16;
    float s[16];
    const float* cin = carry + (size_t)bh * 4096 + i * 64 + j0;
    for (int jj = 0; jj < 16; ++jj) s[jj] = cin[jj];
    for (int cc = 0; cc < NC_; ++cc) {
        float* so = Sin + ((size_t)bh * NC_ + cc) * 4096 + i * 64 + j0;
        for (int jj = 0; jj < 16; ++jj) so[jj] = s[jj];
        float P = Pws[bh * NC_ + cc];
        const float* mm = Mws + ((size_t)bh * NC_ + cc) * 4096 + i * 64 + j0;
        for (int jj = 0; jj < 16; ++jj) s[jj] = s[jj] * P + mm[jj];
    }
    float* co = carry_out + (size_t)bh * 4096 + i * 64 + j0;
    for (int jj = 0; jj < 16; ++jj) co[jj] = s[jj];
}

// ---------------- scan phase C: attn = p_t*(S_in q_t) + intra-triangular ----
__global__ __launch_bounds__(256) void scan_attn_k(const float* __restrict__ Q,
                                                   const float* __restrict__ Kq,
                                                   const float* __restrict__ V,
                                                   const float* __restrict__ mask,
                                                   const float* __restrict__ Sin,
                                                   float* __restrict__ attn) {
    int bid = blockIdx.x;
    int c = bid & (NC_ - 1), h = (bid >> 3) & (H_ - 1), b = bid >> 6;
    __shared__ float sq[64][64];
    __shared__ float sk[64][64];   // k, later reused for weighted scores
    __shared__ float sv[64][64];
    __shared__ float scv[64], pp[64];
    int tid = threadIdx.x;
    for (int it = 0; it < 4; ++it) {
        int idx = tid + it * 256;
        int t = idx >> 4, d4 = idx & 15;
        size_t base = ((size_t)(b * S_ + c * 64 + t) * (H_ * HD_)) + h * 64 + d4 * 4;
        *(float4*)&sq[t][d4 * 4] = *(const float4*)&Q[base];
        *(float4*)&sk[t][d4 * 4] = *(const float4*)&Kq[base];
        *(float4*)&sv[t][d4 * 4] = *(const float4*)&V[base];
    }
    if (tid < 64) scv[tid] = 1.f - mask[b * S_ + c * 64 + tid];
    __syncthreads();
    if (tid == 0) {
        float p = 1.f;
        for (int t = 0; t < 64; ++t) { p *= scv[t]; pp[t] = p; }
    }
    __syncthreads();
    // phase 1: weighted lower-tri scores sw[u][t] = (k_u . q_t) * prod_{u+1..t} c
    int u = tid >> 2, t0 = (tid & 3) * 16;
    float sw[16];
#pragma unroll
    for (int tt = 0; tt < 16; ++tt) {
        int t = t0 + tt;
        if (t < u) { sw[tt] = 0.f; continue; }
        float dot = 0.f;
        for (int d = 0; d < 64; ++d) dot += sk[u][d] * sq[t][d];
        float w = 1.f;
        for (int x = u + 1; x <= t; ++x) w *= scv[x];
        sw[tt] = dot * w;
    }
    __syncthreads();
    for (int tt = 0; tt < 16; ++tt) sk[u][t0 + tt] = sw[tt];
    __syncthreads();
    // phase 2: attn[t][i] = pp[t]*dot(Sin[i,:],q_t) + sum_u sw[u][t]*v_u[i]
    int t = tid >> 2, i0 = (tid & 3) * 16;
    float outv[16];
    const float* srow0 = Sin + ((size_t)((b * H_ + h) * NC_ + c)) * 4096;
    float ptv = pp[t];
#pragma unroll
    for (int ii = 0; ii < 16; ++ii) {
        const float* srow = srow0 + (i0 + ii) * 64;
        float a = 0.f;
        for (int d = 0; d < 64; ++d) a += srow[d] * sq[t][d];
        outv[ii] = a * ptv;
    }
    for (int u2 = 0; u2 < 64; ++u2) {
        float s = sk[u2][t];
#pragma unroll
        for (int ii = 0; ii < 16; ++ii) outv[ii] += s * sv[u2][i0 + ii];
    }
    float* ao = attn + ((size_t)(b * S_ + c * 64 + t) * (H_ * HD_)) + h * 64 + i0;
    for (int ii = 0; ii < 16; ++ii) ao[ii] = outv[ii];
}

// ---------------------------------------------------------------------------
extern "C" void kernel_launch(void* const* d_in, const int* in_sizes, int n_in,
                              void* d_out, int out_size, void* d_ws, size_t ws_size,
                              hipStream_t stream) {
    const float* inputs  = (const float*)d_in[0];
    const float* mask    = (const float*)d_in[1];
    const float* carry   = (const float*)d_in[2];
    const float* ln1     = (const float*)d_in[3];
    const float* Wq      = (const float*)d_in[4];
    const float* Wk      = (const float*)d_in[5];
    const float* Wv      = (const float*)d_in[6];
    const float* attn_ln = (const float*)d_in[7];
    const float* Wo      = (const float*)d_in[8];
    const float* bo      = (const float*)d_in[9];
    const float* ln2     = (const float*)d_in[10];
    const float* Wg      = (const float*)d_in[11];
    const float* Wu      = (const float*)d_in[12];
    const float* Wd      = (const float*)d_in[13];

    float* out_carry = (float*)d_out;                         // B*H*HD*HD = 65536
    float* out_x     = (float*)d_out + (size_t)B_ * H_ * HD_ * HD_;

    float* ws   = (float*)d_ws;
    float* X    = ws;                    // 1024x512
    float* Qb   = ws + 524288;
    float* Kb   = ws + 1048576;
    float* Vb   = ws + 1572864;
    float* Mws  = ws + 2097152;          // 16*8*4096
    float* Pws  = ws + 2621440;          // 128
    float* Sin  = ws + 2621568;          // 16*8*4096
    float* Attn = X;                     // X dead after QKV GEMMs
    float* AttnN= Qb;                    // Q dead after scan
    float* X1   = Kb;                    // K dead after scan
    float* X2N  = Vb;                    // V dead after scan
    float* Hbuf = Mws;                   // M/P/Sin dead after scan; 1024x2048

    const int rows = B_ * S_;            // 1024

    rmsnorm_k<<<dim3(rows), dim3(128), 0, stream>>>(inputs, ln1, X);
    gemm_k<<<dim3(D_/64, rows/64), dim3(256), 0, stream>>>(X, Wq, Qb, rows, D_, D_, nullptr, nullptr, 1);
    gemm_k<<<dim3(D_/64, rows/64), dim3(256), 0, stream>>>(X, Wk, Kb, rows, D_, D_, nullptr, nullptr, 1);
    gemm_k<<<dim3(D_/64, rows/64), dim3(256), 0, stream>>>(X, Wv, Vb, rows, D_, D_, nullptr, nullptr, 0);
    scan_chunk_outer_k<<<dim3(B_*H_*NC_), dim3(256), 0, stream>>>(Kb, Vb, mask, Mws, Pws);
    scan_prefix_k<<<dim3(B_*H_), dim3(256), 0, stream>>>(carry, Mws, Pws, Sin, out_carry);
    scan_attn_k<<<dim3(B_*H_*NC_), dim3(256), 0, stream>>>(Qb, Kb, Vb, mask, Sin, Attn);
    rmsnorm_k<<<dim3(rows), dim3(128), 0, stream>>>(Attn, attn_ln, AttnN);
    gemm_k<<<dim3(D_/64, rows/64), dim3(256), 0, stream>>>(AttnN, Wo, X1, rows, D_, D_, bo, inputs, 0);
    rmsnorm_k<<<dim3(rows), dim3(128), 0, stream>>>(X1, ln2, X2N);
    gemm_dual_silu_k<<<dim3(FFN_/64, rows/64), dim3(256), 0, stream>>>(X2N, Wg, Wu, Hbuf, rows, FFN_, D_);
    gemm_k<<<dim3(D_/64, rows/64), dim3(256), 0, stream>>>(Hbuf, Wd, out_x, rows, D_, FFN_, nullptr, X1, 0);
}

// Round 2
// 240.700 us; speedup vs baseline: 1.5274x; 1.5274x over previous
//
#include <hip/hip_runtime.h>
#include <math.h>

typedef __bf16 bf16x8 __attribute__((ext_vector_type(8)));
typedef float  f32x4  __attribute__((ext_vector_type(4)));

constexpr int B_=2, S_=512, D_=512, H_=8, HD_=64, FFN_=2048, NC_=8;
constexpr float EPS_=1e-6f;

__device__ __forceinline__ __bf16 f2bf(float f){
    union{float f;unsigned u;}x; x.f=f;
    unsigned r=(x.u+0x7fffu+((x.u>>16)&1u))>>16;
    union{unsigned short s;__bf16 b;}y; y.s=(unsigned short)r; return y.b;
}
__device__ __forceinline__ float bf2f(unsigned short s){
    union{unsigned u;float f;}x; x.u=((unsigned)s)<<16; return x.f;
}
__device__ __forceinline__ void bf8_f32(uint4 p, float* o){
    unsigned w[4]={p.x,p.y,p.z,p.w};
#pragma unroll
    for(int i=0;i<4;i++){ o[2*i]=bf2f((unsigned short)(w[i]&0xffffu)); o[2*i+1]=bf2f((unsigned short)(w[i]>>16)); }
}
__device__ __forceinline__ f32x4 MF(bf16x8 a, bf16x8 b, f32x4 c){
    return __builtin_amdgcn_mfma_f32_16x16x32_bf16(a,b,c,0,0,0);
}
#define GLOAD16(g,l) __builtin_amdgcn_global_load_lds((__attribute__((address_space(1))) const void*)(g),(__attribute__((address_space(3))) void*)(l),16,0,0)

// ---------------- weight prep: fp32 [K][N] -> bf16 [N][K] -------------------
__global__ __launch_bounds__(256) void wprep_k(const float* __restrict__ Wg,
    const float* __restrict__ Wu, const float* __restrict__ Wd,
    const float* __restrict__ Wq, const float* __restrict__ Wk,
    const float* __restrict__ Wv, const float* __restrict__ Wo,
    __bf16* __restrict__ WT){
    int t = blockIdx.x;
    const float* src; __bf16* dst; int K,N,lt;
    if      (t<256){ src=Wg; dst=WT;          K=512;  N=2048; lt=t; }
    else if (t<512){ src=Wu; dst=WT+1048576;  K=512;  N=2048; lt=t-256; }
    else if (t<768){ src=Wd; dst=WT+2097152;  K=2048; N=512;  lt=t-512; }
    else if (t<832){ src=Wq; dst=WT+3145728;  K=512;  N=512;  lt=t-768; }
    else if (t<896){ src=Wk; dst=WT+3407872;  K=512;  N=512;  lt=t-832; }
    else if (t<960){ src=Wv; dst=WT+3670016;  K=512;  N=512;  lt=t-896; }
    else           { src=Wo; dst=WT+3932160;  K=512;  N=512;  lt=t-960; }
    int nt64 = N>>6, tk = lt/nt64, tn = lt%nt64;
    __shared__ __bf16 s[64][72];
    int tid = threadIdx.x;
    {
        int jk = tid>>2, jn0 = (tid&3)*16;
        const float* p = src + (size_t)(tk*64+jk)*N + tn*64 + jn0;
        float4 a0=((const float4*)p)[0], a1=((const float4*)p)[1],
               a2=((const float4*)p)[2], a3=((const float4*)p)[3];
        bf16x8 w0, w1;
        w0[0]=f2bf(a0.x); w0[1]=f2bf(a0.y); w0[2]=f2bf(a0.z); w0[3]=f2bf(a0.w);
        w0[4]=f2bf(a1.x); w0[5]=f2bf(a1.y); w0[6]=f2bf(a1.z); w0[7]=f2bf(a1.w);
        w1[0]=f2bf(a2.x); w1[1]=f2bf(a2.y); w1[2]=f2bf(a2.z); w1[3]=f2bf(a2.w);
        w1[4]=f2bf(a3.x); w1[5]=f2bf(a3.y); w1[6]=f2bf(a3.z); w1[7]=f2bf(a3.w);
        *(bf16x8*)&s[jk][jn0] = w0; *(bf16x8*)&s[jk][jn0+8] = w1;
    }
    __syncthreads();
    {
        int jn = tid>>2, jk0 = (tid&3)*16;
        bf16x8 w0, w1;
#pragma unroll
        for(int j=0;j<8;j++){ w0[j]=s[jk0+j][jn]; w1[j]=s[jk0+8+j][jn]; }
        __bf16* q = dst + (size_t)(tn*64+jn)*K + tk*64 + jk0;
        *(bf16x8*)q = w0; *(bf16x8*)(q+8) = w1;
    }
}

// ---------------- row RMS scales: rs[row] = rsqrt(mean(x^2)+eps) ------------
__global__ __launch_bounds__(256) void rowrms_f32_k(const float* __restrict__ X, float* __restrict__ rs){
    int row = blockIdx.x*4 + (threadIdx.x>>6), lane = threadIdx.x&63;
    const float4* p = (const float4*)(X + (size_t)row*D_) + lane*2;
    float4 a=p[0], b=p[1];
    float ss = a.x*a.x+a.y*a.y+a.z*a.z+a.w*a.w + b.x*b.x+b.y*b.y+b.z*b.z+b.w*b.w;
    for(int off=32; off>0; off>>=1) ss += __shfl_down(ss, off, 64);
    if(lane==0) rs[row] = rsqrtf(ss/(float)D_ + EPS_);
}
__global__ __launch_bounds__(256) void rowrms_bf16_k(const __bf16* __restrict__ X, float* __restrict__ rs){
    int row = blockIdx.x*4 + (threadIdx.x>>6), lane = threadIdx.x&63;
    uint4 p = *(const uint4*)(X + (size_t)row*D_ + lane*8);
    float v[8]; bf8_f32(p, v);
    float ss = 0.f;
#pragma unroll
    for(int i=0;i<8;i++) ss += v[i]*v[i];
    for(int off=32; off>0; off>>=1) ss += __shfl_down(ss, off, 64);
    if(lane==0) rs[row] = rsqrtf(ss/(float)D_ + EPS_);
}

// ---------------- GEMM building blocks (64x64 tile, BK=64, 4 waves) ---------
// LDS halves [64][32] bf16 (row 64B): balanced banks + global_load_lds friendly.
__device__ __forceinline__ void stageB_async(const __bf16* __restrict__ Bt, int n0, int K, int kk,
                                             __bf16* sB0, __bf16* sB1, int wave, int lane){
    int row = (wave<<4) + (lane>>2), kq = (lane&3)<<3;
    const __bf16* g = Bt + (size_t)(n0+row)*K + kk + kq;
    GLOAD16(g,      sB0 + (wave<<9));
    GLOAD16(g + 32, sB1 + (wave<<9));
}
// fused-RMS A stage: A'[m][k] = in[m][k] * rs[m] * g[k], fp32 input
__device__ __forceinline__ void stageA_rms_f32(const float* __restrict__ A, const float* __restrict__ rs,
        const float* __restrict__ g, int m0, int K, int kk, __bf16* sA0, __bf16* sA1, int tid){
    int row = tid>>2, kq = (tid&3)<<4;
    float r = rs[m0+row];
    const float4* p = (const float4*)(A + (size_t)(m0+row)*K + kk + kq);
    const float4* gp = (const float4*)(g + kk + kq);
    float4 a[4] = {p[0],p[1],p[2],p[3]};
    float4 gg[4] = {gp[0],gp[1],gp[2],gp[3]};
    bf16x8 w0, w1;
    w0[0]=f2bf(a[0].x*r*gg[0].x); w0[1]=f2bf(a[0].y*r*gg[0].y);
    w0[2]=f2bf(a[0].z*r*gg[0].z); w0[3]=f2bf(a[0].w*r*gg[0].w);
    w0[4]=f2bf(a[1].x*r*gg[1].x); w0[5]=f2bf(a[1].y*r*gg[1].y);
    w0[6]=f2bf(a[1].z*r*gg[1].z); w0[7]=f2bf(a[1].w*r*gg[1].w);
    w1[0]=f2bf(a[2].x*r*gg[2].x); w1[1]=f2bf(a[2].y*r*gg[2].y);
    w1[2]=f2bf(a[2].z*r*gg[2].z); w1[3]=f2bf(a[2].w*r*gg[2].w);
    w1[4]=f2bf(a[3].x*r*gg[3].x); w1[5]=f2bf(a[3].y*r*gg[3].y);
    w1[6]=f2bf(a[3].z*r*gg[3].z); w1[7]=f2bf(a[3].w*r*gg[3].w);
    __bf16* d = (kq<32) ? (sA0 + row*32 + kq) : (sA1 + row*32 + kq-32);
    *(bf16x8*)d = w0; *(bf16x8*)(d+8) = w1;
}
// fused-RMS A stage, bf16 input
__device__ __forceinline__ void stageA_rms_bf16(const __bf16* __restrict__ A, const float* __restrict__ rs,
        const float* __restrict__ g, int m0, int K, int kk, __bf16* sA0, __bf16* sA1, int tid){
    int row = tid>>2, kq = (tid&3)<<4;
    float r = rs[m0+row];
    const __bf16* p = A + (size_t)(m0+row)*K + kk + kq;
    float v[16]; bf8_f32(*(const uint4*)p, v); bf8_f32(*(const uint4*)(p+8), v+8);
    const float4* gp = (const float4*)(g + kk + kq);
    float4 gg[4] = {gp[0],gp[1],gp[2],gp[3]};
    float gf[16] = {gg[0].x,gg[0].y,gg[0].z,gg[0].w, gg[1].x,gg[1].y,gg[1].z,gg[1].w,
                    gg[2].x,gg[2].y,gg[2].z,gg[2].w, gg[3].x,gg[3].y,gg[3].z,gg[3].w};
    bf16x8 w0, w1;
#pragma unroll
    for(int j=0;j<8;j++){ w0[j]=f2bf(v[j]*r*gf[j]); w1[j]=f2bf(v[8+j]*r*gf[8+j]); }
    __bf16* d = (kq<32) ? (sA0 + row*32 + kq) : (sA1 + row*32 + kq-32);
    *(bf16x8*)d = w0; *(bf16x8*)(d+8) = w1;
}
__device__ __forceinline__ void mfma_tile(const __bf16* sA0, const __bf16* sA1,
        const __bf16* sB0, const __bf16* sB1, int wave, int lane, f32x4 acc[4]){
    int ar = (((wave<<4)+(lane&15))<<5) + ((lane>>4)<<3);
    bf16x8 a0 = *(const bf16x8*)(sA0+ar);
    bf16x8 a1 = *(const bf16x8*)(sA1+ar);
#pragma unroll
    for(int nt=0;nt<4;nt++){
        int br = (((nt<<4)+(lane&15))<<5) + ((lane>>4)<<3);
        acc[nt] = MF(a0, *(const bf16x8*)(sB0+br), acc[nt]);
        acc[nt] = MF(a1, *(const bf16x8*)(sB1+br), acc[nt]);
    }
}

// ---------------- QKV fused GEMM (relu on q,k) ------------------------------
__global__ __launch_bounds__(256) void gemm_qkv_k(const float* __restrict__ in,
        const float* __restrict__ rs1, const float* __restrict__ ln1,
        const __bf16* __restrict__ Bt, __bf16* __restrict__ Qb,
        __bf16* __restrict__ Kb, __bf16* __restrict__ Vb){
    __shared__ __bf16 sA0[2048], sA1[2048], sB0[2048], sB1[2048];
    int tid=threadIdx.x, wave=tid>>6, lane=tid&63;
    int n0 = blockIdx.x*64, m0 = blockIdx.y*64;
    f32x4 acc[4] = {};
    for(int kk=0; kk<512; kk+=64){
        stageB_async(Bt, n0, 512, kk, sB0, sB1, wave, lane);
        stageA_rms_f32(in, rs1, ln1, m0, 512, kk, sA0, sA1, tid);
        __syncthreads();
        mfma_tile(sA0,sA1,sB0,sB1,wave,lane,acc);
        __syncthreads();
    }
    int seg = n0>>9, nc = n0&511;
    __bf16* Out = seg==0 ? Qb : (seg==1 ? Kb : Vb);
    bool rl = seg<2;
    int r0 = (wave<<4) + ((lane>>4)<<2);
#pragma unroll
    for(int nt=0;nt<4;nt++){
        int col = nc + nt*16 + (lane&15);
#pragma unroll
        for(int r=0;r<4;r++){
            float v = acc[nt][r]; if(rl) v = fmaxf(v,0.f);
            Out[(size_t)(m0+r0+r)*512 + col] = f2bf(v);
        }
    }
}

// ---------------- Wo GEMM: out_x = attn_n@Wo + bo + skip ; X1 = bf16(out_x) -
__global__ __launch_bounds__(256) void gemm_wo_k(const __bf16* __restrict__ attn,
        const float* __restrict__ rs2, const float* __restrict__ aln,
        const __bf16* __restrict__ Bt, const float* __restrict__ bo,
        const float* __restrict__ skip, float* __restrict__ outx, __bf16* __restrict__ X1){
    __shared__ __bf16 sA0[2048], sA1[2048], sB0[2048], sB1[2048];
    int tid=threadIdx.x, wave=tid>>6, lane=tid&63;
    int n0 = blockIdx.x*64, m0 = blockIdx.y*64;
    f32x4 acc[4] = {};
    for(int kk=0; kk<512; kk+=64){
        stageB_async(Bt, n0, 512, kk, sB0, sB1, wave, lane);
        stageA_rms_bf16(attn, rs2, aln, m0, 512, kk, sA0, sA1, tid);
        __syncthreads();
        mfma_tile(sA0,sA1,sB0,sB1,wave,lane,acc);
        __syncthreads();
    }
    int r0 = (wave<<4) + ((lane>>4)<<2);
#pragma unroll
    for(int nt=0;nt<4;nt++){
        int col = n0 + nt*16 + (lane&15);
#pragma unroll
        for(int r=0;r<4;r++){
            int row = m0+r0+r;
            float v = acc[nt][r] + bo[col] + skip[(size_t)row*512+col];
            outx[(size_t)row*512+col] = v;
            X1[(size_t)row*512+col] = f2bf(v);
        }
    }
}

// ---------------- FFN dual GEMM + silu(g)*u ---------------------------------
__global__ __launch_bounds__(256) void gemm_dual_k(const __bf16* __restrict__ X1,
        const float* __restrict__ rs3, const float* __restrict__ ln2,
        const __bf16* __restrict__ Gt, const __bf16* __restrict__ Ut,
        __bf16* __restrict__ Hb){
    __shared__ __bf16 sA0[2048], sA1[2048], sG0[2048], sG1[2048], sU0[2048], sU1[2048];
    int tid=threadIdx.x, wave=tid>>6, lane=tid&63;
    int n0 = blockIdx.x*64, m0 = blockIdx.y*64;
    f32x4 ag[4] = {}, au[4] = {};
    for(int kk=0; kk<512; kk+=64){
        stageB_async(Gt, n0, 512, kk, sG0, sG1, wave, lane);
        stageB_async(Ut, n0, 512, kk, sU0, sU1, wave, lane);
        stageA_rms_bf16(X1, rs3, ln2, m0, 512, kk, sA0, sA1, tid);
        __syncthreads();
        {
            int ar = (((wave<<4)+(lane&15))<<5) + ((lane>>4)<<3);
            bf16x8 a0 = *(const bf16x8*)(sA0+ar);
            bf16x8 a1 = *(const bf16x8*)(sA1+ar);
#pragma unroll
            for(int nt=0;nt<4;nt++){
                int br = (((nt<<4)+(lane&15))<<5) + ((lane>>4)<<3);
                ag[nt] = MF(a0, *(const bf16x8*)(sG0+br), ag[nt]);
                ag[nt] = MF(a1, *(const bf16x8*)(sG1+br), ag[nt]);
                au[nt] = MF(a0, *(const bf16x8*)(sU0+br), au[nt]);
                au[nt] = MF(a1, *(const bf16x8*)(sU1+br), au[nt]);
            }
        }
        __syncthreads();
    }
    int r0 = (wave<<4) + ((lane>>4)<<2);
#pragma unroll
    for(int nt=0;nt<4;nt++){
        int col = n0 + nt*16 + (lane&15);
#pragma unroll
        for(int r=0;r<4;r++){
            float gv = ag[nt][r], uv = au[nt][r];
            float hv = (gv / (1.f + __expf(-gv))) * uv;
            Hb[(size_t)(m0+r0+r)*FFN_ + col] = f2bf(hv);
        }
    }
}

// ---------------- Wd GEMM, split-K=4, atomicAdd into out_x ------------------
__global__ __launch_bounds__(256) void gemm_wd_k(const __bf16* __restrict__ Hb,
        const __bf16* __restrict__ Bt, float* __restrict__ outx){
    __shared__ __bf16 sA0[2048], sA1[2048], sB0[2048], sB1[2048];
    int tid=threadIdx.x, wave=tid>>6, lane=tid&63;
    int n0 = blockIdx.x*64, m0 = blockIdx.y*64, ks = blockIdx.z*512;
    f32x4 acc[4] = {};
    int row = (wave<<4) + (lane>>2), kq = (lane&3)<<3;
    for(int kk=ks; kk<ks+512; kk+=64){
        stageB_async(Bt, n0, FFN_, kk, sB0, sB1, wave, lane);
        const __bf16* g = Hb + (size_t)(m0+row)*FFN_ + kk + kq;
        GLOAD16(g,      sA0 + (wave<<9));
        GLOAD16(g + 32, sA1 + (wave<<9));
        __syncthreads();
        mfma_tile(sA0,sA1,sB0,sB1,wave,lane,acc);
        __syncthreads();
    }
    int r0 = (wave<<4) + ((lane>>4)<<2);
#pragma unroll
    for(int nt=0;nt<4;nt++){
        int col = n0 + nt*16 + (lane&15);
#pragma unroll
        for(int r=0;r<4;r++)
            atomicAdd(&outx[(size_t)(m0+r0+r)*512 + col], acc[nt][r]);
    }
}

// ---------------- scan A: per-chunk decayed outer-product sums --------------
__global__ __launch_bounds__(256) void scanA_k(const __bf16* __restrict__ Kb,
        const __bf16* __restrict__ Vb, const float* __restrict__ mask,
        __bf16* __restrict__ MS, float* __restrict__ Pws){
    int bid = blockIdx.x;
    int c = bid&7, h = (bid>>3)&7, b = bid>>6;
    __shared__ float sk[64][64], sv[64][64];
    __shared__ float scv[64], ssp[64];
    int tid = threadIdx.x;
    {
        int row = tid>>2, c16 = (tid&3)*16;
        size_t base = (size_t)(b*512 + c*64 + row)*512 + h*64 + c16;
        bf8_f32(*(const uint4*)(Kb+base), &sk[row][c16]);
        bf8_f32(*(const uint4*)(Kb+base+8), &sk[row][c16+8]);
        bf8_f32(*(const uint4*)(Vb+base), &sv[row][c16]);
        bf8_f32(*(const uint4*)(Vb+base+8), &sv[row][c16+8]);
    }
    if(tid<64) scv[tid] = 1.f - mask[b*512 + c*64 + tid];
    __syncthreads();
    if(tid==0){
        float sp = 1.f;
        for(int t=63;t>=0;--t){ ssp[t]=sp; sp*=scv[t]; }
        Pws[bid] = sp;
    }
    __syncthreads();
    int i = tid>>2, j0 = (tid&3)*16;
    float m[16];
#pragma unroll
    for(int j=0;j<16;j++) m[j]=0.f;
    for(int t=0;t<64;t++){
        float vv = sv[t][i]*ssp[t];
#pragma unroll
        for(int j=0;j<16;j++) m[j] += vv*sk[t][j0+j];
    }
    __bf16* o = MS + (size_t)bid*4096 + i*64 + j0;
    for(int j=0;j<16;j++) o[j] = f2bf(m[j]);
}

// ---------------- scan B: inter-chunk prefix (in-place MS->Sin) + carry -----
__global__ __launch_bounds__(256) void scanB_k(const float* __restrict__ carry,
        __bf16* __restrict__ MS, const float* __restrict__ Pws,
        float* __restrict__ carry_out){
    int bh = blockIdx.x, tid = threadIdx.x;
    int i = tid>>2, j0 = (tid&3)*16;
    float s[16];
    const float* ci = carry + (size_t)bh*4096 + i*64 + j0;
    for(int j=0;j<16;j++) s[j]=ci[j];
    for(int cc=0; cc<NC_; ++cc){
        __bf16* p = MS + ((size_t)bh*NC_+cc)*4096 + i*64 + j0;
        float P = Pws[bh*NC_+cc];
        for(int j=0;j<16;j++){
            float m = bf2f(*(const unsigned short*)&p[j]);
            p[j] = f2bf(s[j]);          // Sin = state before this chunk
            s[j] = s[j]*P + m;
        }
    }
    float* co = carry_out + (size_t)bh*4096 + i*64 + j0;
    for(int j=0;j<16;j++) co[j]=s[j];
}

// ---------------- scan C: attn = p_t*(Sin q_t) + intra-chunk triangular -----
__global__ __launch_bounds__(256) void scanC_k(const __bf16* __restrict__ Qb,
        const __bf16* __restrict__ Kb, const __bf16* __restrict__ Vb,
        const float* __restrict__ mask, const __bf16* __restrict__ MS,
        __bf16* __restrict__ attn){
    int bid = blockIdx.x;
    int c = bid&7, h = (bid>>3)&7, b = bid>>6;
    __shared__ float sq[64][64], sk[64][64], sv[64][64];
    __shared__ float scv[64], pp[64];
    int tid = threadIdx.x;
    {
        int row = tid>>2, c16 = (tid&3)*16;
        size_t base = (size_t)(b*512 + c*64 + row)*512 + h*64 + c16;
        bf8_f32(*(const uint4*)(Qb+base), &sq[row][c16]);
        bf8_f32(*(const uint4*)(Qb+base+8), &sq[row][c16+8]);
        bf8_f32(*(const uint4*)(Kb+base), &sk[row][c16]);
        bf8_f32(*(const uint4*)(Kb+base+8), &sk[row][c16+8]);
        bf8_f32(*(const uint4*)(Vb+base), &sv[row][c16]);
        bf8_f32(*(const uint4*)(Vb+base+8), &sv[row][c16+8]);
    }
    if(tid<64) scv[tid] = 1.f - mask[b*512 + c*64 + tid];
    __syncthreads();
    if(tid==0){
        float p=1.f;
        for(int t=0;t<64;t++){ p*=scv[t]; pp[t]=p; }
    }
    __syncthreads();
    int u = tid>>2, t0 = (tid&3)*16;
    float sw[16];
#pragma unroll
    for(int tt=0;tt<16;tt++){
        int t = t0+tt;
        if(t<u){ sw[tt]=0.f; continue; }
        float dot=0.f;
        for(int d=0; d<64; d++) dot += sk[u][d]*sq[t][d];
        float w=1.f;
        for(int x=u+1; x<=t; x++) w *= scv[x];
        sw[tt] = dot*w;
    }
    __syncthreads();
    for(int tt=0;tt<16;tt++) sk[u][t0+tt] = sw[tt];
    __syncthreads();
    int t = tid>>2, i0 = (tid&3)*16;
    float outv[16];
    const __bf16* srow0 = MS + ((size_t)((b*H_+h)*NC_+c))*4096;
    float ptv = pp[t];
#pragma unroll
    for(int ii=0; ii<16; ii++){
        const __bf16* srow = srow0 + (i0+ii)*64;
        float a=0.f;
        for(int d=0; d<64; d++) a += bf2f(*(const unsigned short*)&srow[d])*sq[t][d];
        outv[ii] = a*ptv;
    }
    for(int u2=0; u2<64; u2++){
        float s = sk[u2][t];
#pragma unroll
        for(int ii=0; ii<16; ii++) outv[ii] += s*sv[u2][i0+ii];
    }
    __bf16* ao = attn + (size_t)(b*512 + c*64 + t)*512 + h*64 + i0;
    for(int ii=0; ii<16; ii++) ao[ii] = f2bf(outv[ii]);
}

// ---------------------------------------------------------------------------
extern "C" void kernel_launch(void* const* d_in, const int* in_sizes, int n_in,
                              void* d_out, int out_size, void* d_ws, size_t ws_size,
                              hipStream_t stream) {
    const float* inputs  = (const float*)d_in[0];
    const float* mask    = (const float*)d_in[1];
    const float* carry   = (const float*)d_in[2];
    const float* ln1     = (const float*)d_in[3];
    const float* Wq      = (const float*)d_in[4];
    const float* Wk      = (const float*)d_in[5];
    const float* Wv      = (const float*)d_in[6];
    const float* attn_ln = (const float*)d_in[7];
    const float* Wo      = (const float*)d_in[8];
    const float* bo      = (const float*)d_in[9];
    const float* ln2     = (const float*)d_in[10];
    const float* Wg      = (const float*)d_in[11];
    const float* Wu      = (const float*)d_in[12];
    const float* Wd      = (const float*)d_in[13];

    float* out_carry = (float*)d_out;                  // 2*8*64*64 = 65536
    float* out_x     = (float*)d_out + 65536;          // 1024*512

    __bf16* wb = (__bf16*)d_ws;
    float*  wf = (float*)d_ws;
    // bf16-element offsets into ws (high-water 12.6 MB, within proven budget)
    __bf16* WgT   = wb;             // [2048][512]
    __bf16* WuT   = wb + 1048576;   // [2048][512]
    __bf16* WdT   = wb + 2097152;   // [512][2048]
    __bf16* WqkvT = wb + 3145728;   // [1536][512] (q,k,v stacked)
    __bf16* WoT   = wb + 3932160;   // [512][512]
    __bf16* Qb    = wb + 4194304;   // [1024][512]; later attn (self-aliased)
    __bf16* Kb    = wb + 4718592;
    __bf16* Vb    = wb + 5242880;   // later X1
    __bf16* Hb    = wb + 3145728;   // [1024][2048] over dead WqkvT/WoT/Qb/Kb
    __bf16* MS    = wb + 5767168;   // [16][8][4096] Mws -> Sin in place
    float*  Pws   = wf + 3145728;
    float*  rs1   = wf + 3145856;
    float*  rs2   = wf + 3146880;
    float*  rs3   = wf + 3147904;

    wprep_k<<<dim3(1024), dim3(256), 0, stream>>>(Wg,Wu,Wd,Wq,Wk,Wv,Wo, wb);
    rowrms_f32_k<<<dim3(256), dim3(256), 0, stream>>>(inputs, rs1);
    gemm_qkv_k<<<dim3(24,16), dim3(256), 0, stream>>>(inputs, rs1, ln1, WqkvT, Qb, Kb, Vb);
    scanA_k<<<dim3(128), dim3(256), 0, stream>>>(Kb, Vb, mask, MS, Pws);
    scanB_k<<<dim3(16), dim3(256), 0, stream>>>(carry, MS, Pws, out_carry);
    scanC_k<<<dim3(128), dim3(256), 0, stream>>>(Qb, Kb, Vb, mask, MS, /*attn->*/Qb);
    rowrms_bf16_k<<<dim3(256), dim3(256), 0, stream>>>(Qb, rs2);
    gemm_wo_k<<<dim3(8,16), dim3(256), 0, stream>>>(Qb, rs2, attn_ln, WoT, bo, inputs, out_x, /*X1=*/Vb);
    rowrms_bf16_k<<<dim3(256), dim3(256), 0, stream>>>(Vb, rs3);
    gemm_dual_k<<<dim3(32,16), dim3(256), 0, stream>>>(Vb, rs3, ln2, WgT, WuT, Hb);
    gemm_wd_k<<<dim3(8,16,4), dim3(256), 0, stream>>>(Hb, WdT, out_x);
}

// Round 3
// 165.997 us; speedup vs baseline: 2.2147x; 1.4500x over previous
//
#include <hip/hip_runtime.h>
#include <math.h>

typedef __bf16 bf16x8 __attribute__((ext_vector_type(8)));
typedef float  f32x4  __attribute__((ext_vector_type(4)));

constexpr int B_=2, S_=512, D_=512, H_=8, HD_=64, FFN_=2048, NC_=8;
constexpr float EPS_=1e-6f;

__device__ __forceinline__ __bf16 f2bf(float f){
    union{float f;unsigned u;}x; x.f=f;
    unsigned r=(x.u+0x7fffu+((x.u>>16)&1u))>>16;
    union{unsigned short s;__bf16 b;}y; y.s=(unsigned short)r; return y.b;
}
__device__ __forceinline__ float bf2f(unsigned short s){
    union{unsigned u;float f;}x; x.u=((unsigned)s)<<16; return x.f;
}
__device__ __forceinline__ void bf8_f32(uint4 p, float* o){
    unsigned w[4]={p.x,p.y,p.z,p.w};
#pragma unroll
    for(int i=0;i<4;i++){ o[2*i]=bf2f((unsigned short)(w[i]&0xffffu)); o[2*i+1]=bf2f((unsigned short)(w[i]>>16)); }
}
__device__ __forceinline__ f32x4 MF(bf16x8 a, bf16x8 b, f32x4 c){
    return __builtin_amdgcn_mfma_f32_16x16x32_bf16(a,b,c,0,0,0);
}
#define GLOAD16(g,l) __builtin_amdgcn_global_load_lds((__attribute__((address_space(1))) const void*)(g),(__attribute__((address_space(3))) void*)(l),16,0,0)

// ---------------- weight prep: fp32 [K][N] -> bf16 [N][K] -------------------
__global__ __launch_bounds__(256) void wprep_k(const float* __restrict__ Wg,
    const float* __restrict__ Wu, const float* __restrict__ Wd,
    const float* __restrict__ Wq, const float* __restrict__ Wk,
    const float* __restrict__ Wv, const float* __restrict__ Wo,
    __bf16* __restrict__ WT){
    int t = blockIdx.x;
    const float* src; __bf16* dst; int K,N,lt;
    if      (t<256){ src=Wg; dst=WT;          K=512;  N=2048; lt=t; }
    else if (t<512){ src=Wu; dst=WT+1048576;  K=512;  N=2048; lt=t-256; }
    else if (t<768){ src=Wd; dst=WT+2097152;  K=2048; N=512;  lt=t-512; }
    else if (t<832){ src=Wq; dst=WT+3145728;  K=512;  N=512;  lt=t-768; }
    else if (t<896){ src=Wk; dst=WT+3407872;  K=512;  N=512;  lt=t-832; }
    else if (t<960){ src=Wv; dst=WT+3670016;  K=512;  N=512;  lt=t-896; }
    else           { src=Wo; dst=WT+3932160;  K=512;  N=512;  lt=t-960; }
    int nt64 = N>>6, tk = lt/nt64, tn = lt%nt64;
    __shared__ __bf16 s[64][72];
    int tid = threadIdx.x;
    {
        int jk = tid>>2, jn0 = (tid&3)*16;
        const float* p = src + (size_t)(tk*64+jk)*N + tn*64 + jn0;
        float4 a0=((const float4*)p)[0], a1=((const float4*)p)[1],
               a2=((const float4*)p)[2], a3=((const float4*)p)[3];
        bf16x8 w0, w1;
        w0[0]=f2bf(a0.x); w0[1]=f2bf(a0.y); w0[2]=f2bf(a0.z); w0[3]=f2bf(a0.w);
        w0[4]=f2bf(a1.x); w0[5]=f2bf(a1.y); w0[6]=f2bf(a1.z); w0[7]=f2bf(a1.w);
        w1[0]=f2bf(a2.x); w1[1]=f2bf(a2.y); w1[2]=f2bf(a2.z); w1[3]=f2bf(a2.w);
        w1[4]=f2bf(a3.x); w1[5]=f2bf(a3.y); w1[6]=f2bf(a3.z); w1[7]=f2bf(a3.w);
        *(bf16x8*)&s[jk][jn0] = w0; *(bf16x8*)&s[jk][jn0+8] = w1;
    }
    __syncthreads();
    {
        int jn = tid>>2, jk0 = (tid&3)*16;
        bf16x8 w0, w1;
#pragma unroll
        for(int j=0;j<8;j++){ w0[j]=s[jk0+j][jn]; w1[j]=s[jk0+8+j][jn]; }
        __bf16* q = dst + (size_t)(tn*64+jn)*K + tk*64 + jk0;
        *(bf16x8*)q = w0; *(bf16x8*)(q+8) = w1;
    }
}

// ---------------- row RMS scales: rs[row] = rsqrt(mean(x^2)+eps) ------------
__global__ __launch_bounds__(256) void rowrms_f32_k(const float* __restrict__ X, float* __restrict__ rs){
    int row = blockIdx.x*4 + (threadIdx.x>>6), lane = threadIdx.x&63;
    const float4* p = (const float4*)(X + (size_t)row*D_) + lane*2;
    float4 a=p[0], b=p[1];
    float ss = a.x*a.x+a.y*a.y+a.z*a.z+a.w*a.w + b.x*b.x+b.y*b.y+b.z*b.z+b.w*b.w;
    for(int off=32; off>0; off>>=1) ss += __shfl_down(ss, off, 64);
    if(lane==0) rs[row] = rsqrtf(ss/(float)D_ + EPS_);
}
__global__ __launch_bounds__(256) void rowrms_bf16_k(const __bf16* __restrict__ X, float* __restrict__ rs){
    int row = blockIdx.x*4 + (threadIdx.x>>6), lane = threadIdx.x&63;
    uint4 p = *(const uint4*)(X + (size_t)row*D_ + lane*8);
    float v[8]; bf8_f32(p, v);
    float ss = 0.f;
#pragma unroll
    for(int i=0;i<8;i++) ss += v[i]*v[i];
    for(int off=32; off>0; off>>=1) ss += __shfl_down(ss, off, 64);
    if(lane==0) rs[row] = rsqrtf(ss/(float)D_ + EPS_);
}

// ---------------- GEMM building blocks (64x64 tile, BK=64, 4 waves) ---------
// LDS halves [64][32] bf16 (row 64B): balanced banks + global_load_lds friendly.
__device__ __forceinline__ void stageB_async(const __bf16* __restrict__ Bt, int n0, int K, int kk,
                                             __bf16* sB0, __bf16* sB1, int wave, int lane){
    int row = (wave<<4) + (lane>>2), kq = (lane&3)<<3;
    const __bf16* g = Bt + (size_t)(n0+row)*K + kk + kq;
    GLOAD16(g,      sB0 + (wave<<9));
    GLOAD16(g + 32, sB1 + (wave<<9));
}
// fused-RMS A stage: A'[m][k] = in[m][k] * rs[m] * g[k], fp32 input
__device__ __forceinline__ void stageA_rms_f32(const float* __restrict__ A, const float* __restrict__ rs,
        const float* __restrict__ g, int m0, int K, int kk, __bf16* sA0, __bf16* sA1, int tid){
    int row = tid>>2, kq = (tid&3)<<4;
    float r = rs[m0+row];
    const float4* p = (const float4*)(A + (size_t)(m0+row)*K + kk + kq);
    const float4* gp = (const float4*)(g + kk + kq);
    float4 a[4] = {p[0],p[1],p[2],p[3]};
    float4 gg[4] = {gp[0],gp[1],gp[2],gp[3]};
    bf16x8 w0, w1;
    w0[0]=f2bf(a[0].x*r*gg[0].x); w0[1]=f2bf(a[0].y*r*gg[0].y);
    w0[2]=f2bf(a[0].z*r*gg[0].z); w0[3]=f2bf(a[0].w*r*gg[0].w);
    w0[4]=f2bf(a[1].x*r*gg[1].x); w0[5]=f2bf(a[1].y*r*gg[1].y);
    w0[6]=f2bf(a[1].z*r*gg[1].z); w0[7]=f2bf(a[1].w*r*gg[1].w);
    w1[0]=f2bf(a[2].x*r*gg[2].x); w1[1]=f2bf(a[2].y*r*gg[2].y);
    w1[2]=f2bf(a[2].z*r*gg[2].z); w1[3]=f2bf(a[2].w*r*gg[2].w);
    w1[4]=f2bf(a[3].x*r*gg[3].x); w1[5]=f2bf(a[3].y*r*gg[3].y);
    w1[6]=f2bf(a[3].z*r*gg[3].z); w1[7]=f2bf(a[3].w*r*gg[3].w);
    __bf16* d = (kq<32) ? (sA0 + row*32 + kq) : (sA1 + row*32 + kq-32);
    *(bf16x8*)d = w0; *(bf16x8*)(d+8) = w1;
}
// fused-RMS A stage, bf16 input
__device__ __forceinline__ void stageA_rms_bf16(const __bf16* __restrict__ A, const float* __restrict__ rs,
        const float* __restrict__ g, int m0, int K, int kk, __bf16* sA0, __bf16* sA1, int tid){
    int row = tid>>2, kq = (tid&3)<<4;
    float r = rs[m0+row];
    const __bf16* p = A + (size_t)(m0+row)*K + kk + kq;
    float v[16]; bf8_f32(*(const uint4*)p, v); bf8_f32(*(const uint4*)(p+8), v+8);
    const float4* gp = (const float4*)(g + kk + kq);
    float4 gg[4] = {gp[0],gp[1],gp[2],gp[3]};
    float gf[16] = {gg[0].x,gg[0].y,gg[0].z,gg[0].w, gg[1].x,gg[1].y,gg[1].z,gg[1].w,
                    gg[2].x,gg[2].y,gg[2].z,gg[2].w, gg[3].x,gg[3].y,gg[3].z,gg[3].w};
    bf16x8 w0, w1;
#pragma unroll
    for(int j=0;j<8;j++){ w0[j]=f2bf(v[j]*r*gf[j]); w1[j]=f2bf(v[8+j]*r*gf[8+j]); }
    __bf16* d = (kq<32) ? (sA0 + row*32 + kq) : (sA1 + row*32 + kq-32);
    *(bf16x8*)d = w0; *(bf16x8*)(d+8) = w1;
}
__device__ __forceinline__ void mfma_tile(const __bf16* sA0, const __bf16* sA1,
        const __bf16* sB0, const __bf16* sB1, int wave, int lane, f32x4 acc[4]){
    int ar = (((wave<<4)+(lane&15))<<5) + ((lane>>4)<<3);
    bf16x8 a0 = *(const bf16x8*)(sA0+ar);
    bf16x8 a1 = *(const bf16x8*)(sA1+ar);
#pragma unroll
    for(int nt=0;nt<4;nt++){
        int br = (((nt<<4)+(lane&15))<<5) + ((lane>>4)<<3);
        acc[nt] = MF(a0, *(const bf16x8*)(sB0+br), acc[nt]);
        acc[nt] = MF(a1, *(const bf16x8*)(sB1+br), acc[nt]);
    }
}

// ---------------- QKV fused GEMM (relu on q,k) ------------------------------
__global__ __launch_bounds__(256) void gemm_qkv_k(const float* __restrict__ in,
        const float* __restrict__ rs1, const float* __restrict__ ln1,
        const __bf16* __restrict__ Bt, __bf16* __restrict__ Qb,
        __bf16* __restrict__ Kb, __bf16* __restrict__ Vb){
    __shared__ __bf16 sA0[2048], sA1[2048], sB0[2048], sB1[2048];
    int tid=threadIdx.x, wave=tid>>6, lane=tid&63;
    int n0 = blockIdx.x*64, m0 = blockIdx.y*64;
    f32x4 acc[4] = {};
    for(int kk=0; kk<512; kk+=64){
        stageB_async(Bt, n0, 512, kk, sB0, sB1, wave, lane);
        stageA_rms_f32(in, rs1, ln1, m0, 512, kk, sA0, sA1, tid);
        __syncthreads();
        mfma_tile(sA0,sA1,sB0,sB1,wave,lane,acc);
        __syncthreads();
    }
    int seg = n0>>9, nc = n0&511;
    __bf16* Out = seg==0 ? Qb : (seg==1 ? Kb : Vb);
    bool rl = seg<2;
    int r0 = (wave<<4) + ((lane>>4)<<2);
#pragma unroll
    for(int nt=0;nt<4;nt++){
        int col = nc + nt*16 + (lane&15);
#pragma unroll
        for(int r=0;r<4;r++){
            float v = acc[nt][r]; if(rl) v = fmaxf(v,0.f);
            Out[(size_t)(m0+r0+r)*512 + col] = f2bf(v);
        }
    }
}

// ---------------- Wo GEMM: out_x = attn_n@Wo + bo + skip ; X1 = bf16(out_x) -
__global__ __launch_bounds__(256) void gemm_wo_k(const __bf16* __restrict__ attn,
        const float* __restrict__ rs2, const float* __restrict__ aln,
        const __bf16* __restrict__ Bt, const float* __restrict__ bo,
        const float* __restrict__ skip, float* __restrict__ outx, __bf16* __restrict__ X1){
    __shared__ __bf16 sA0[2048], sA1[2048], sB0[2048], sB1[2048];
    int tid=threadIdx.x, wave=tid>>6, lane=tid&63;
    int n0 = blockIdx.x*64, m0 = blockIdx.y*64;
    f32x4 acc[4] = {};
    for(int kk=0; kk<512; kk+=64){
        stageB_async(Bt, n0, 512, kk, sB0, sB1, wave, lane);
        stageA_rms_bf16(attn, rs2, aln, m0, 512, kk, sA0, sA1, tid);
        __syncthreads();
        mfma_tile(sA0,sA1,sB0,sB1,wave,lane,acc);
        __syncthreads();
    }
    int r0 = (wave<<4) + ((lane>>4)<<2);
#pragma unroll
    for(int nt=0;nt<4;nt++){
        int col = n0 + nt*16 + (lane&15);
#pragma unroll
        for(int r=0;r<4;r++){
            int row = m0+r0+r;
            float v = acc[nt][r] + bo[col] + skip[(size_t)row*512+col];
            outx[(size_t)row*512+col] = v;
            X1[(size_t)row*512+col] = f2bf(v);
        }
    }
}

// ---------------- FFN dual GEMM + silu(g)*u ---------------------------------
__global__ __launch_bounds__(256) void gemm_dual_k(const __bf16* __restrict__ X1,
        const float* __restrict__ rs3, const float* __restrict__ ln2,
        const __bf16* __restrict__ Gt, const __bf16* __restrict__ Ut,
        __bf16* __restrict__ Hb){
    __shared__ __bf16 sA0[2048], sA1[2048], sG0[2048], sG1[2048], sU0[2048], sU1[2048];
    int tid=threadIdx.x, wave=tid>>6, lane=tid&63;
    int n0 = blockIdx.x*64, m0 = blockIdx.y*64;
    f32x4 ag[4] = {}, au[4] = {};
    for(int kk=0; kk<512; kk+=64){
        stageB_async(Gt, n0, 512, kk, sG0, sG1, wave, lane);
        stageB_async(Ut, n0, 512, kk, sU0, sU1, wave, lane);
        stageA_rms_bf16(X1, rs3, ln2, m0, 512, kk, sA0, sA1, tid);
        __syncthreads();
        {
            int ar = (((wave<<4)+(lane&15))<<5) + ((lane>>4)<<3);
            bf16x8 a0 = *(const bf16x8*)(sA0+ar);
            bf16x8 a1 = *(const bf16x8*)(sA1+ar);
#pragma unroll
            for(int nt=0;nt<4;nt++){
                int br = (((nt<<4)+(lane&15))<<5) + ((lane>>4)<<3);
                ag[nt] = MF(a0, *(const bf16x8*)(sG0+br), ag[nt]);
                ag[nt] = MF(a1, *(const bf16x8*)(sG1+br), ag[nt]);
                au[nt] = MF(a0, *(const bf16x8*)(sU0+br), au[nt]);
                au[nt] = MF(a1, *(const bf16x8*)(sU1+br), au[nt]);
            }
        }
        __syncthreads();
    }
    int r0 = (wave<<4) + ((lane>>4)<<2);
#pragma unroll
    for(int nt=0;nt<4;nt++){
        int col = n0 + nt*16 + (lane&15);
#pragma unroll
        for(int r=0;r<4;r++){
            float gv = ag[nt][r], uv = au[nt][r];
            float hv = (gv / (1.f + __expf(-gv))) * uv;
            Hb[(size_t)(m0+r0+r)*FFN_ + col] = f2bf(hv);
        }
    }
}

// ---------------- Wd GEMM, split-K=4, atomicAdd into out_x ------------------
__global__ __launch_bounds__(256) void gemm_wd_k(const __bf16* __restrict__ Hb,
        const __bf16* __restrict__ Bt, float* __restrict__ outx){
    __shared__ __bf16 sA0[2048], sA1[2048], sB0[2048], sB1[2048];
    int tid=threadIdx.x, wave=tid>>6, lane=tid&63;
    int n0 = blockIdx.x*64, m0 = blockIdx.y*64, ks = blockIdx.z*512;
    f32x4 acc[4] = {};
    int row = (wave<<4) + (lane>>2), kq = (lane&3)<<3;
    for(int kk=ks; kk<ks+512; kk+=64){
        stageB_async(Bt, n0, FFN_, kk, sB0, sB1, wave, lane);
        const __bf16* g = Hb + (size_t)(m0+row)*FFN_ + kk + kq;
        GLOAD16(g,      sA0 + (wave<<9));
        GLOAD16(g + 32, sA1 + (wave<<9));
        __syncthreads();
        mfma_tile(sA0,sA1,sB0,sB1,wave,lane,acc);
        __syncthreads();
    }
    int r0 = (wave<<4) + ((lane>>4)<<2);
#pragma unroll
    for(int nt=0;nt<4;nt++){
        int col = n0 + nt*16 + (lane&15);
#pragma unroll
        for(int r=0;r<4;r++)
            atomicAdd(&outx[(size_t)(m0+r0+r)*512 + col], acc[nt][r]);
    }
}

// ---------------- scan A (MFMA): M[i][j] = sum_t ssp[t] v[t][i] k[t][j] -----
__global__ __launch_bounds__(256) void scanA_k(const __bf16* __restrict__ Kb,
        const __bf16* __restrict__ Vb, const float* __restrict__ mask,
        __bf16* __restrict__ MS, float* __restrict__ Pws){
    int bid = blockIdx.x;
    int c = bid&7, h = (bid>>3)&7, b = bid>>6;
    __shared__ __bf16 sKT0[2048], sKT1[2048], sVT0[2048], sVT1[2048];
    __shared__ float scv[64], ssp[64];
    int tid = threadIdx.x, wave = tid>>6, lane = tid&63;
    const __bf16* Kg = Kb + (size_t)(b*512 + c*64)*512 + h*64;
    const __bf16* Vg = Vb + (size_t)(b*512 + c*64)*512 + h*64;
    if(tid<64) scv[tid] = 1.f - mask[b*512 + c*64 + tid];
    __syncthreads();
    if(tid==0){
        float sp = 1.f;
        for(int t=63;t>=0;--t){ ssp[t]=sp; sp*=scv[t]; }
        Pws[bid] = sp;
    }
    __syncthreads();
    // transposed staging: sKT[j][t] = K[t][j]; sVT[i][t] = V[t][i]*ssp[t]
#pragma unroll
    for(int p=0;p<2;p++){
        int t = (tid>>3) + p*32, i0 = (tid&7)*8;
        uint4 kr = *(const uint4*)(Kg + (size_t)t*512 + i0);
        uint4 vr = *(const uint4*)(Vg + (size_t)t*512 + i0);
        const __bf16* kp = (const __bf16*)&kr;
        const unsigned short* vp = (const unsigned short*)&vr;
        float sp = ssp[t];
        __bf16* kh = p ? sKT1 : sKT0;
        __bf16* vh = p ? sVT1 : sVT0;
#pragma unroll
        for(int j=0;j<8;j++){
            kh[(i0+j)*32 + (t&31)] = kp[j];
            vh[(i0+j)*32 + (t&31)] = f2bf(bf2f(vp[j])*sp);
        }
    }
    __syncthreads();
    f32x4 am[4] = {};
    mfma_tile(sVT0, sVT1, sKT0, sKT1, wave, lane, am);   // C[m=i][n=j]
    __bf16* Mo = MS + (size_t)bid*4096;
    int r0 = (wave<<4) + ((lane>>4)<<2);
#pragma unroll
    for(int nt=0;nt<4;nt++){
        int j = nt*16 + (lane&15);
#pragma unroll
        for(int r=0;r<4;r++) Mo[(size_t)(r0+r)*64 + j] = f2bf(am[nt][r]);
    }
}

// ---------------- scan B: inter-chunk prefix (in-place MS->Sin) + carry -----
__global__ __launch_bounds__(256) void scanB_k(const float* __restrict__ carry,
        __bf16* __restrict__ MS, const float* __restrict__ Pws,
        float* __restrict__ carry_out){
    int bh = blockIdx.x, tid = threadIdx.x;
    int i = tid>>2, j0 = (tid&3)*16;
    float s[16];
    const float* ci = carry + (size_t)bh*4096 + i*64 + j0;
    for(int j=0;j<16;j++) s[j]=ci[j];
    for(int cc=0; cc<NC_; ++cc){
        __bf16* p = MS + ((size_t)bh*NC_+cc)*4096 + i*64 + j0;
        float P = Pws[bh*NC_+cc];
        for(int j=0;j<16;j++){
            float m = bf2f(*(const unsigned short*)&p[j]);
            p[j] = f2bf(s[j]);          // Sin = state before this chunk
            s[j] = s[j]*P + m;
        }
    }
    float* co = carry_out + (size_t)bh*4096 + i*64 + j0;
    for(int j=0;j<16;j++) co[j]=s[j];
}

// ---------------- scan C (MFMA): attn = pp[t]*(Sin q_t) + lower-tri PV ------
__global__ __launch_bounds__(256) void scanC_k(const __bf16* __restrict__ Qb,
        const __bf16* __restrict__ Kb, const __bf16* __restrict__ Vb,
        const float* __restrict__ mask, const __bf16* __restrict__ MS,
        __bf16* __restrict__ attn){
    int bid = blockIdx.x;
    int c = bid&7, h = (bid>>3)&7, b = bid>>6;
    __shared__ __bf16 sQ0[2048], sQ1[2048], sK0[2048], sK1[2048];
    __shared__ __bf16 sS0[2048], sS1[2048];          // Sin [i][d]
    __shared__ __bf16 sVT0[2048], sVT1[2048];        // V^T [i][u]
    __shared__ __bf16 sW0[2048], sW1[2048];          // sw^T [t][u]
    __shared__ float Wtab[64][64];
    __shared__ float scv[64], pp[64];
    int tid = threadIdx.x, wave = tid>>6, lane = tid&63;
    const __bf16* Qg = Qb + (size_t)(b*512 + c*64)*512 + h*64;
    const __bf16* Kg = Kb + (size_t)(b*512 + c*64)*512 + h*64;
    const __bf16* Vg = Vb + (size_t)(b*512 + c*64)*512 + h*64;
    const __bf16* Sg = MS + ((size_t)((b*H_+h)*NC_ + c))*4096;

    stageB_async(Qg, 0, 512, 0, sQ0, sQ1, wave, lane);
    stageB_async(Kg, 0, 512, 0, sK0, sK1, wave, lane);
    stageB_async(Sg, 0, 64,  0, sS0, sS1, wave, lane);
    if(tid<64) scv[tid] = 1.f - mask[b*512 + c*64 + tid];
    // V transpose via registers (coalesced reads, scalar transposed writes)
#pragma unroll
    for(int p=0;p<2;p++){
        int u = (tid>>3) + p*32, i0 = (tid&7)*8;
        uint4 vr = *(const uint4*)(Vg + (size_t)u*512 + i0);
        const __bf16* vp = (const __bf16*)&vr;
        __bf16* vh = p ? sVT1 : sVT0;
#pragma unroll
        for(int j=0;j<8;j++) vh[(i0+j)*32 + (u&31)] = vp[j];
    }
    __syncthreads();   // drains GLOAD16 + LDS writes; scv visible
    if(tid<64){
        int u = tid; float w = 1.f;
        for(int t=0;t<64;t++){
            if(t>u) w *= scv[t];
            Wtab[u][t] = (t<u) ? 0.f : w;
        }
    }
    if(tid==64){
        float p=1.f;
        for(int t=0;t<64;t++){ p*=scv[t]; pp[t]=p; }
    }
    // phase 1: S[u][t] = k_u . q_t
    f32x4 sc[4] = {};
    mfma_tile(sK0, sK1, sQ0, sQ1, wave, lane, sc);   // C[m=u][n=t]
    __syncthreads();   // Wtab/pp ready
    // apply decay weights, store sw^T[t][u] to LDS
    {
        int u0 = (wave<<4) + ((lane>>4)<<2);
#pragma unroll
        for(int nt=0;nt<4;nt++){
            int t = nt*16 + (lane&15);
#pragma unroll
            for(int r=0;r<4;r++){
                int u = u0 + r;
                float v = sc[nt][r] * Wtab[u][t];
                ((u<32) ? sW0 : sW1)[t*32 + (u&31)] = f2bf(v);
            }
        }
    }
    __syncthreads();
    // phase 2: intra = sw^T @ V^T-frag ; phase 3: inter = Q @ Sin-frag
    f32x4 aI[4] = {}, aX[4] = {};
    mfma_tile(sW0, sW1, sVT0, sVT1, wave, lane, aI); // C[m=t][n=i]
    mfma_tile(sQ0, sQ1, sS0, sS1, wave, lane, aX);   // C[m=t][n=i]
    int t0 = (wave<<4) + ((lane>>4)<<2);
#pragma unroll
    for(int nt=0;nt<4;nt++){
        int i = nt*16 + (lane&15);
#pragma unroll
        for(int r=0;r<4;r++){
            int t = t0 + r;
            float o = aI[nt][r] + aX[nt][r]*pp[t];
            attn[(size_t)(b*512 + c*64 + t)*512 + h*64 + i] = f2bf(o);
        }
    }
}

// ---------------------------------------------------------------------------
extern "C" void kernel_launch(void* const* d_in, const int* in_sizes, int n_in,
                              void* d_out, int out_size, void* d_ws, size_t ws_size,
                              hipStream_t stream) {
    const float* inputs  = (const float*)d_in[0];
    const float* mask    = (const float*)d_in[1];
    const float* carry   = (const float*)d_in[2];
    const float* ln1     = (const float*)d_in[3];
    const float* Wq      = (const float*)d_in[4];
    const float* Wk      = (const float*)d_in[5];
    const float* Wv      = (const float*)d_in[6];
    const float* attn_ln = (const float*)d_in[7];
    const float* Wo      = (const float*)d_in[8];
    const float* bo      = (const float*)d_in[9];
    const float* ln2     = (const float*)d_in[10];
    const float* Wg      = (const float*)d_in[11];
    const float* Wu      = (const float*)d_in[12];
    const float* Wd      = (const float*)d_in[13];

    float* out_carry = (float*)d_out;                  // 2*8*64*64 = 65536
    float* out_x     = (float*)d_out + 65536;          // 1024*512

    __bf16* wb = (__bf16*)d_ws;
    float*  wf = (float*)d_ws;
    __bf16* WgT   = wb;             // [2048][512]
    __bf16* WuT   = wb + 1048576;   // [2048][512]
    __bf16* WdT   = wb + 2097152;   // [512][2048]
    __bf16* WqkvT = wb + 3145728;   // [1536][512] (q,k,v stacked)
    __bf16* WoT   = wb + 3932160;   // [512][512]
    __bf16* Qb    = wb + 4194304;   // [1024][512]; later attn (self-aliased)
    __bf16* Kb    = wb + 4718592;
    __bf16* Vb    = wb + 5242880;   // later X1
    __bf16* Hb    = wb + 3145728;   // [1024][2048] over dead WqkvT/WoT/Qb/Kb
    __bf16* MS    = wb + 5767168;   // [16][8][4096] Mws -> Sin in place
    float*  Pws   = wf + 3145728;
    float*  rs1   = wf + 3145856;
    float*  rs2   = wf + 3146880;
    float*  rs3   = wf + 3147904;

    wprep_k<<<dim3(1024), dim3(256), 0, stream>>>(Wg,Wu,Wd,Wq,Wk,Wv,Wo, wb);
    rowrms_f32_k<<<dim3(256), dim3(256), 0, stream>>>(inputs, rs1);
    gemm_qkv_k<<<dim3(24,16), dim3(256), 0, stream>>>(inputs, rs1, ln1, WqkvT, Qb, Kb, Vb);
    scanA_k<<<dim3(128), dim3(256), 0, stream>>>(Kb, Vb, mask, MS, Pws);
    scanB_k<<<dim3(16), dim3(256), 0, stream>>>(carry, MS, Pws, out_carry);
    scanC_k<<<dim3(128), dim3(256), 0, stream>>>(Qb, Kb, Vb, mask, MS, /*attn->*/Qb);
    rowrms_bf16_k<<<dim3(256), dim3(256), 0, stream>>>(Qb, rs2);
    gemm_wo_k<<<dim3(8,16), dim3(256), 0, stream>>>(Qb, rs2, attn_ln, WoT, bo, inputs, out_x, /*X1=*/Vb);
    rowrms_bf16_k<<<dim3(256), dim3(256), 0, stream>>>(Vb, rs3);
    gemm_dual_k<<<dim3(32,16), dim3(256), 0, stream>>>(Vb, rs3, ln2, WgT, WuT, Hb);
    gemm_wd_k<<<dim3(8,16,4), dim3(256), 0, stream>>>(Hb, WdT, out_x);
}